// Round 6
// baseline (5442.691 us; speedup 1.0000x reference)
//
#include <hip/hip_runtime.h>
#include <hip/hip_bf16.h>
#include <stdint.h>

typedef __bf16 bf16_t;
typedef __bf16 bf16x8v __attribute__((ext_vector_type(8)));
typedef __bf16 bf16x4v __attribute__((ext_vector_type(4)));
typedef float f32x4 __attribute__((ext_vector_type(4)));

#define DEV __device__ __forceinline__

typedef const __attribute__((address_space(1))) void gl_void_t;
typedef __attribute__((address_space(3))) void lds_void_t;

DEV void gll16(const void* g, void* l) {
    __builtin_amdgcn_global_load_lds((gl_void_t*)g, (lds_void_t*)l, 16, 0, 0);
}

DEV f32x4 mfma16(bf16x8v a, bf16x8v b, f32x4 c) {
    return __builtin_amdgcn_mfma_f32_16x16x32_bf16(a, b, c, 0, 0, 0);
}

// ---------------------------------------------------------------------------
// fp32 -> bf16 conversion (grid-stride, float4)
// ---------------------------------------------------------------------------
__global__ __launch_bounds__(256)
void f32_to_bf16_k(const float* __restrict__ in, bf16_t* __restrict__ out, size_t n4) {
    size_t stride = (size_t)gridDim.x * 256;
    for (size_t i = (size_t)blockIdx.x * 256 + threadIdx.x; i < n4; i += stride) {
        float4 v = ((const float4*)in)[i];
        bf16x4v o;
        o[0] = (bf16_t)v.x; o[1] = (bf16_t)v.y; o[2] = (bf16_t)v.z; o[3] = (bf16_t)v.w;
        ((bf16x4v*)out)[i] = o;
    }
}

// ---------------------------------------------------------------------------
// fp32 -> (hi, lo) bf16 split: hi = bf16(v), lo = bf16(v - hi).  hi+lo ~ v to 2^-18.
// ---------------------------------------------------------------------------
__global__ __launch_bounds__(256)
void split_k(const float* __restrict__ in, bf16_t* __restrict__ hi,
             bf16_t* __restrict__ lo, size_t n4) {
    size_t stride = (size_t)gridDim.x * 256;
    for (size_t i = (size_t)blockIdx.x * 256 + threadIdx.x; i < n4; i += stride) {
        float4 v = ((const float4*)in)[i];
        bf16x4v h, l;
#pragma unroll
        for (int j = 0; j < 4; ++j) {
            float vv = (&v.x)[j];
            bf16_t hb = (bf16_t)vv;
            h[j] = hb;
            l[j] = (bf16_t)(vv - (float)hb);
        }
        ((bf16x4v*)hi)[i] = h;
        ((bf16x4v*)lo)[i] = l;
    }
}

// ---------------------------------------------------------------------------
// RMSNorm: fp32 [2048][2048] -> bf16 (SPLIT=0) or split hi/lo bf16 (SPLIT=1)
// ---------------------------------------------------------------------------
template<int SPLIT>
__global__ __launch_bounds__(256)
void rmsnorm_k(const float* __restrict__ x, const float* __restrict__ w,
               bf16_t* __restrict__ out, bf16_t* __restrict__ out_lo) {
    const int row = blockIdx.x, t = threadIdx.x;
    const float4* xr = (const float4*)(x + (size_t)row * 2048);
    float4 v0 = xr[t], v1 = xr[t + 256];
    float ss = v0.x*v0.x + v0.y*v0.y + v0.z*v0.z + v0.w*v0.w
             + v1.x*v1.x + v1.y*v1.y + v1.z*v1.z + v1.w*v1.w;
    for (int m = 32; m; m >>= 1) ss += __shfl_xor(ss, m);
    __shared__ float red[4];
    if ((t & 63) == 0) red[t >> 6] = ss;
    __syncthreads();
    ss = red[0] + red[1] + red[2] + red[3];
    float rinv = rsqrtf(ss * (1.0f / 2048.0f) + 1e-6f);
    const float4* wr4 = (const float4*)w;
    float4 w0 = wr4[t], w1 = wr4[t + 256];
    bf16x4v o0, o1, l0, l1;
#pragma unroll
    for (int j = 0; j < 4; ++j) {
        float y0 = (&v0.x)[j] * rinv * (&w0.x)[j];
        float y1 = (&v1.x)[j] * rinv * (&w1.x)[j];
        bf16_t h0 = (bf16_t)y0, h1 = (bf16_t)y1;
        o0[j] = h0; o1[j] = h1;
        if (SPLIT) { l0[j] = (bf16_t)(y0 - (float)h0); l1[j] = (bf16_t)(y1 - (float)h1); }
    }
    *(bf16x4v*)(out + (size_t)row * 2048 + t * 4) = o0;
    *(bf16x4v*)(out + (size_t)row * 2048 + 1024 + t * 4) = o1;
    if (SPLIT) {
        *(bf16x4v*)(out_lo + (size_t)row * 2048 + t * 4) = l0;
        *(bf16x4v*)(out_lo + (size_t)row * 2048 + 1024 + t * 4) = l1;
    }
}

// ---------------------------------------------------------------------------
// GEMM: C[M][N] = A[M][K](bf16) * B[N][K]^T(bf16).  m97-structure.
// EPI 0: Cf = acc          EPI 1: Cb = bf16(acc)
// EPI 3: Cf += comb[row*8] * acc   (comb pre-offset by expert)
// EPI 4: Cf += acc
// EPI 5: o = Cf + resid + acc; Cf = o; out2 = o   (final split-GEMM pass)
// ---------------------------------------------------------------------------
template<int EPI>
__global__ __launch_bounds__(256)
void gemm_bt(const bf16_t* __restrict__ A, const bf16_t* __restrict__ B,
             float* __restrict__ Cf, bf16_t* __restrict__ Cb,
             const float* __restrict__ resid, float* __restrict__ out2,
             const float* __restrict__ comb,
             int M, int N, int K) {
    __shared__ bf16_t As[128 * 64];
    __shared__ bf16_t Bs[128 * 64];
    const int t = threadIdx.x;
    const int w = t >> 6, l = t & 63;
    const int lr = l & 15, lg = l >> 4;
    const int wr = w >> 1, wc = w & 1;
    const int bm = blockIdx.y, bn = blockIdx.x;
    const bf16_t* Ab = A + (size_t)bm * 128 * K;
    const bf16_t* Bb = B + (size_t)bn * 128 * K;
    const int srow = t >> 3;
    const int scol = (t & 7) * 8;
    f32x4 acc[4][4] = {};
    for (int kt = 0; kt < K; kt += 64) {
        __syncthreads();
#pragma unroll
        for (int c = 0; c < 4; ++c) {
            gll16(Ab + (size_t)(c * 32 + srow) * K + kt + scol, As + (c * 32 + srow) * 64 + scol);
            gll16(Bb + (size_t)(c * 32 + srow) * K + kt + scol, Bs + (c * 32 + srow) * 64 + scol);
        }
        __syncthreads();
#pragma unroll
        for (int kk = 0; kk < 2; ++kk) {
            bf16x8v af[4], bfr[4];
#pragma unroll
            for (int m = 0; m < 4; ++m)
                af[m] = *(const bf16x8v*)(As + (wr * 64 + m * 16 + lr) * 64 + kk * 32 + lg * 8);
#pragma unroll
            for (int n = 0; n < 4; ++n)
                bfr[n] = *(const bf16x8v*)(Bs + (wc * 64 + n * 16 + lr) * 64 + kk * 32 + lg * 8);
#pragma unroll
            for (int m = 0; m < 4; ++m)
#pragma unroll
                for (int n = 0; n < 4; ++n)
                    acc[m][n] = mfma16(af[m], bfr[n], acc[m][n]);
        }
    }
#pragma unroll
    for (int m = 0; m < 4; ++m) {
#pragma unroll
        for (int r = 0; r < 4; ++r) {
            int gr = bm * 128 + wr * 64 + m * 16 + lg * 4 + r;
            float cw = 0.f;
            if (EPI == 3) cw = comb[(size_t)gr * 8];
#pragma unroll
            for (int n = 0; n < 4; ++n) {
                int gc = bn * 128 + wc * 64 + n * 16 + lr;
                size_t off = (size_t)gr * N + gc;
                float v = acc[m][n][r];
                if (EPI == 0) {
                    Cf[off] = v;
                } else if (EPI == 1) {
                    Cb[off] = (bf16_t)v;
                } else if (EPI == 3) {
                    Cf[off] += cw * v;
                } else if (EPI == 4) {
                    Cf[off] += v;
                } else {
                    float o = Cf[off] + resid[off] + v;
                    Cf[off] = o;
                    out2[off] = o;
                }
            }
        }
    }
}

// ---------------------------------------------------------------------------
// q/k RMSNorm (over 2048 / 512) + partial RoPE (RD=64), all fp32 out:
// qrf[16][2048][128] (pre-scaled by 1/sqrt(128)), krf[4][2048][128],
// vrf[4][2048][128]
// ---------------------------------------------------------------------------
__global__ __launch_bounds__(256)
void qknorm_rope_f32(const float* __restrict__ qkv, const float* __restrict__ qn_w,
                     const float* __restrict__ kn_w, const float* __restrict__ cosb,
                     const float* __restrict__ sinb,
                     float* __restrict__ qrf, float* __restrict__ krf,
                     float* __restrict__ vrf) {
    const int s = blockIdx.x, t = threadIdx.x;
    const float* row = qkv + (size_t)s * 3072;
    float ssq = 0.f;
#pragma unroll
    for (int rep = 0; rep < 8; ++rep) { float v = row[t + rep * 256]; ssq += v * v; }
    float a = row[2048 + t], b = row[2048 + t + 256];
    float ssk = a * a + b * b;
    for (int m = 32; m; m >>= 1) { ssq += __shfl_xor(ssq, m); ssk += __shfl_xor(ssk, m); }
    __shared__ float redq[4], redk[4];
    if ((t & 63) == 0) { redq[t >> 6] = ssq; redk[t >> 6] = ssk; }
    __syncthreads();
    ssq = redq[0] + redq[1] + redq[2] + redq[3];
    ssk = redk[0] + redk[1] + redk[2] + redk[3];
    float rq = rsqrtf(ssq * (1.f / 2048.f) + 1e-6f);
    float rk = rsqrtf(ssk * (1.f / 512.f) + 1e-6f);
#pragma unroll
    for (int rep = 0; rep < 8; ++rep) {
        int i = t + rep * 256;
        int hd = i & 127, hh = i >> 7;
        float v = row[i] * rq * qn_w[i];
        float o;
        if (hd < 64) {
            float vp = row[i ^ 32] * rq * qn_w[i ^ 32];
            float cs = cosb[s * 64 + hd], sn = sinb[s * 64 + hd];
            o = v * cs + ((hd < 32) ? -vp : vp) * sn;
        } else o = v;
        qrf[((size_t)hh * 2048 + s) * 128 + hd] = o * 0.08838834764831845f;
    }
#pragma unroll
    for (int rep = 0; rep < 2; ++rep) {
        int i2 = t + rep * 256;
        int hd = i2 & 127, hh = i2 >> 7;
        float v = row[2048 + i2] * rk * kn_w[i2];
        float o;
        if (hd < 64) {
            float vp = row[2048 + (i2 ^ 32)] * rk * kn_w[i2 ^ 32];
            float cs = cosb[s * 64 + hd], sn = sinb[s * 64 + hd];
            o = v * cs + ((hd < 32) ? -vp : vp) * sn;
        } else o = v;
        krf[((size_t)hh * 2048 + s) * 128 + hd] = o;
    }
#pragma unroll
    for (int rep = 0; rep < 2; ++rep) {
        int i2 = t + rep * 256;
        int hd = i2 & 127, hh = i2 >> 7;
        vrf[((size_t)hh * 2048 + s) * 128 + hd] = row[2560 + i2];
    }
}

// ---------------------------------------------------------------------------
// Exact fp32 attention: one wave per 4 consecutive q rows of one head.
// Online softmax, fp32 end-to-end. K/V rows shared across the 4 q rows.
// ---------------------------------------------------------------------------
__global__ __launch_bounds__(256)
void attn_naive4(const float* __restrict__ qrf, const float* __restrict__ krf,
                 const float* __restrict__ vrf, float* __restrict__ attnf) {
    const int wid = blockIdx.x * 4 + (threadIdx.x >> 6);   // 16*512 waves
    const int l = threadIdx.x & 63;
    const int h = wid >> 9, qg = wid & 511, q0 = qg * 4, hk = h >> 2;
    const float2* Qb = (const float2*)(qrf + ((size_t)h * 2048 + q0) * 128) + l;
    float2 qv[4];
#pragma unroll
    for (int r = 0; r < 4; ++r) qv[r] = Qb[(size_t)r * 64];
    const float2* Kb = (const float2*)(krf + (size_t)hk * 2048 * 128) + l;
    const float2* Vb = (const float2*)(vrf + (size_t)hk * 2048 * 128) + l;
    float m[4], ls[4], a0[4], a1[4];
#pragma unroll
    for (int r = 0; r < 4; ++r) { m[r] = -__builtin_inff(); ls[r] = 0.f; a0[r] = 0.f; a1[r] = 0.f; }
    const int nkv = q0 + 4;
    for (int kv = 0; kv < nkv; ++kv) {
        float2 kx = Kb[(size_t)kv * 64];
        float2 vx = Vb[(size_t)kv * 64];
#pragma unroll
        for (int r = 0; r < 4; ++r) {
            float sc = qv[r].x * kx.x + qv[r].y * kx.y;
            sc += __shfl_xor(sc, 1);  sc += __shfl_xor(sc, 2);
            sc += __shfl_xor(sc, 4);  sc += __shfl_xor(sc, 8);
            sc += __shfl_xor(sc, 16); sc += __shfl_xor(sc, 32);
            if (kv > q0 + r) sc = -__builtin_inff();
            float mn = fmaxf(m[r], sc);
            float scl = __expf(m[r] - mn);
            float p = __expf(sc - mn);
            ls[r] = ls[r] * scl + p;
            a0[r] = a0[r] * scl + p * vx.x;
            a1[r] = a1[r] * scl + p * vx.y;
            m[r] = mn;
        }
    }
#pragma unroll
    for (int r = 0; r < 4; ++r) {
        float inv = 1.f / ls[r];
        float2 o2 = make_float2(a0[r] * inv, a1[r] * inv);
        *((float2*)(attnf + (size_t)(q0 + r) * 2048 + h * 128) + l) = o2;
    }
}

// ---------------------------------------------------------------------------
// Router (fp64): rmsnorm(h)*ln2_w @ gate_w^T -> sigmoid -> top2 -> comb[T][8]
// ---------------------------------------------------------------------------
__global__ __launch_bounds__(256)
void routing_k(const float* __restrict__ h, const float* __restrict__ ln2w,
               const float* __restrict__ gate_w, const float* __restrict__ bias_corr,
               float* __restrict__ comb) {
    const int s = blockIdx.x, t = threadIdx.x;
    const float* xr = h + (size_t)s * 2048;
    float xv[8];
    double ss = 0.0;
#pragma unroll
    for (int rep = 0; rep < 8; ++rep) {
        xv[rep] = xr[t + rep * 256];
        ss += (double)xv[rep] * (double)xv[rep];
    }
    for (int m = 32; m; m >>= 1) ss += __shfl_xor(ss, m);
    __shared__ double redd[4];
    if ((t & 63) == 0) redd[t >> 6] = ss;
    __syncthreads();
    ss = redd[0] + redd[1] + redd[2] + redd[3];
    double rinv = 1.0 / sqrt(ss * (1.0 / 2048.0) + 1e-6);
    double part[8];
#pragma unroll
    for (int e = 0; e < 8; ++e) part[e] = 0.0;
#pragma unroll
    for (int rep = 0; rep < 8; ++rep) {
        int i = t + rep * 256;
        double x = (double)xv[rep] * rinv * (double)ln2w[i];
#pragma unroll
        for (int e = 0; e < 8; ++e)
            part[e] += x * (double)gate_w[e * 2048 + i];
    }
#pragma unroll
    for (int e = 0; e < 8; ++e)
        for (int m = 32; m; m >>= 1) part[e] += __shfl_xor(part[e], m);
    __shared__ double red8[4][8];
    if ((t & 63) == 0) {
#pragma unroll
        for (int e = 0; e < 8; ++e) red8[t >> 6][e] = part[e];
    }
    __syncthreads();
    if (t == 0) {
        double rw[8], sc[8];
#pragma unroll
        for (int e = 0; e < 8; ++e) {
            double v = red8[0][e] + red8[1][e] + red8[2][e] + red8[3][e];
            rw[e] = 1.0 / (1.0 + exp(-v));
            sc[e] = rw[e] + (double)bias_corr[e];
        }
        int i0 = 0;
#pragma unroll
        for (int e = 1; e < 8; ++e) if (sc[e] > sc[i0]) i0 = e;
        int i1 = (i0 == 0) ? 1 : 0;
#pragma unroll
        for (int e = 0; e < 8; ++e) { if (e != i0 && sc[e] > sc[i1]) i1 = e; }
        double denom = rw[i0] + rw[i1];
#pragma unroll
        for (int e = 0; e < 8; ++e) {
            float wv = 0.f;
            if (e == i0) wv = (float)(rw[i0] / denom);
            else if (e == i1) wv = (float)(rw[i1] / denom);
            comb[s * 8 + e] = wv;
        }
    }
}

// ---------------------------------------------------------------------------
// act[e][t][f] = silu(gate[t][e*1024+f]) * up[t][e*1024+f]   (bf16)
// ---------------------------------------------------------------------------
__global__ __launch_bounds__(256)
void silu_mul(const bf16_t* __restrict__ g, const bf16_t* __restrict__ u,
              bf16_t* __restrict__ act) {
    size_t idx = ((size_t)blockIdx.x * 256 + threadIdx.x) * 4;
    int e = (int)(idx >> 21);
    int rem = (int)(idx & ((1u << 21) - 1));
    int tt = rem >> 10, f = rem & 1023;
    size_t gi = (size_t)tt * 8192 + e * 1024 + f;
    bf16x4v gv = *(const bf16x4v*)(g + gi);
    bf16x4v uv = *(const bf16x4v*)(u + gi);
    bf16x4v o;
#pragma unroll
    for (int j = 0; j < 4; ++j) {
        float gf = (float)gv[j], uf = (float)uv[j];
        float sl = gf / (1.f + __expf(-gf));
        o[j] = (bf16_t)(sl * uf);
    }
    *(bf16x4v*)(act + idx) = o;
}

// ---------------------------------------------------------------------------
extern "C" void kernel_launch(void* const* d_in, const int* in_sizes, int n_in,
                              void* d_out, int out_size, void* d_ws, size_t ws_size,
                              hipStream_t stream) {
    const float* hidden = (const float*)d_in[0];
    const float* cosb   = (const float*)d_in[1];
    const float* sinb   = (const float*)d_in[2];
    const float* ln1w   = (const float*)d_in[3];
    const float* ln2w   = (const float*)d_in[4];
    const float* q_w    = (const float*)d_in[5];
    const float* k_w    = (const float*)d_in[6];
    const float* v_w    = (const float*)d_in[7];
    const float* o_w    = (const float*)d_in[8];
    const float* qn_w   = (const float*)d_in[9];
    const float* kn_w   = (const float*)d_in[10];
    const float* gate_w = (const float*)d_in[11];
    const float* w1     = (const float*)d_in[12];
    const float* w2     = (const float*)d_in[13];
    const float* w3     = (const float*)d_in[14];
    const float* bias_c = (const float*)d_in[15];
    float* out = (float*)d_out;
    (void)in_sizes; (void)n_in; (void)out_size; (void)ws_size;

    const size_t MB = 1048576;
    char* ws = (char*)d_ws;
    // fixed region
    float*  hres = (float*)ws;                         // 16 MiB (16.78MB)
    bf16_t* hnb2 = (bf16_t*)(ws + 17 * MB);            // 8.4 MB
    float*  comb = (float*)(ws + 26 * MB);             // 64 KB
    char*   UW   = ws + 27 * MB;                       // 96 MiB weight union
    char*   UA   = ws + 123 * MB;                      // 96 MiB activation union
    // UW phase 1 (attention weights, split)
    bf16_t* whiq = (bf16_t*)(UW);                      // 12.6 MB (3072x2048)
    bf16_t* wloq = (bf16_t*)(UW + 13 * MB);
    bf16_t* wohi = (bf16_t*)(UW + 26 * MB);            // 8.4 MB
    bf16_t* wolo = (bf16_t*)(UW + 35 * MB);
    bf16_t* hnhi = (bf16_t*)(UW + 44 * MB);            // 8.4 MB
    bf16_t* hnlo = (bf16_t*)(UW + 53 * MB);
    // UW phase 2 (MoE weights, bf16) -- written after O-proj completes
    bf16_t* w1b  = (bf16_t*)(UW);                      // 32 MB
    bf16_t* w3b  = (bf16_t*)(UW + 32 * MB);
    bf16_t* w2b  = (bf16_t*)(UW + 64 * MB);
    // UA phase 1
    float*  qkvf  = (float*)(UA);                      // 25.2 MB
    float*  qrf   = (float*)(UA + 26 * MB);            // 16.8 MB
    float*  krf   = (float*)(UA + 43 * MB);            // 4.2 MB
    float*  vrf   = (float*)(UA + 48 * MB);            // 4.2 MB
    float*  attnf = (float*)(UA + 53 * MB);            // 16.8 MB
    bf16_t* aohi  = (bf16_t*)(UA + 70 * MB);           // 8.4 MB
    bf16_t* aolo  = (bf16_t*)(UA + 79 * MB);           // 8.4 MB
    // UA phase 2
    bf16_t* gateb = (bf16_t*)(UA);                     // 32 MB
    bf16_t* upb   = (bf16_t*)(UA + 32 * MB);
    bf16_t* actb  = (bf16_t*)(UA + 64 * MB);

    // ---- attention-path weight splits (hi/lo) ----
    split_k<<<1024, 256, 0, stream>>>(q_w, whiq, wloq, 2048ull * 2048 / 4);
    split_k<<<512, 256, 0, stream>>>(k_w, whiq + 2048ull * 2048, wloq + 2048ull * 2048, 512ull * 2048 / 4);
    split_k<<<512, 256, 0, stream>>>(v_w, whiq + 2560ull * 2048, wloq + 2560ull * 2048, 512ull * 2048 / 4);
    split_k<<<1024, 256, 0, stream>>>(o_w, wohi, wolo, 2048ull * 2048 / 4);

    // ---- ln1 (split) + QKV projection in split-bf16 (4 passes, fp32 out) ----
    rmsnorm_k<1><<<2048, 256, 0, stream>>>(hidden, ln1w, hnhi, hnlo);
    gemm_bt<0><<<dim3(24, 16), 256, 0, stream>>>(hnhi, whiq, qkvf, nullptr, nullptr, nullptr, nullptr, 2048, 3072, 2048);
    gemm_bt<4><<<dim3(24, 16), 256, 0, stream>>>(hnhi, wloq, qkvf, nullptr, nullptr, nullptr, nullptr, 2048, 3072, 2048);
    gemm_bt<4><<<dim3(24, 16), 256, 0, stream>>>(hnlo, whiq, qkvf, nullptr, nullptr, nullptr, nullptr, 2048, 3072, 2048);
    gemm_bt<4><<<dim3(24, 16), 256, 0, stream>>>(hnlo, wloq, qkvf, nullptr, nullptr, nullptr, nullptr, 2048, 3072, 2048);

    // ---- q/k norm + RoPE (fp32) + exact fp32 attention ----
    qknorm_rope_f32<<<2048, 256, 0, stream>>>(qkvf, qn_w, kn_w, cosb, sinb, qrf, krf, vrf);
    attn_naive4<<<2048, 256, 0, stream>>>(qrf, krf, vrf, attnf);

    // ---- O-proj in split-bf16 (4 passes), final pass adds residual, writes out ----
    split_k<<<1024, 256, 0, stream>>>(attnf, aohi, aolo, 2048ull * 2048 / 4);
    gemm_bt<0><<<dim3(16, 16), 256, 0, stream>>>(aohi, wohi, hres, nullptr, nullptr, nullptr, nullptr, 2048, 2048, 2048);
    gemm_bt<4><<<dim3(16, 16), 256, 0, stream>>>(aohi, wolo, hres, nullptr, nullptr, nullptr, nullptr, 2048, 2048, 2048);
    gemm_bt<4><<<dim3(16, 16), 256, 0, stream>>>(aolo, wohi, hres, nullptr, nullptr, nullptr, nullptr, 2048, 2048, 2048);
    gemm_bt<5><<<dim3(16, 16), 256, 0, stream>>>(aolo, wolo, hres, nullptr, hidden, out, nullptr, 2048, 2048, 2048);

    // ---- MoE block (routing fp64 on accurate hres; compute bf16) ----
    rmsnorm_k<0><<<2048, 256, 0, stream>>>(hres, ln2w, hnb2, nullptr);
    routing_k<<<2048, 256, 0, stream>>>(hres, ln2w, gate_w, bias_c, comb);
    f32_to_bf16_k<<<2048, 256, 0, stream>>>(w1, w1b, 8ull * 1024 * 2048 / 4);
    f32_to_bf16_k<<<2048, 256, 0, stream>>>(w3, w3b, 8ull * 1024 * 2048 / 4);
    f32_to_bf16_k<<<2048, 256, 0, stream>>>(w2, w2b, 8ull * 2048 * 1024 / 4);
    gemm_bt<1><<<dim3(64, 16), 256, 0, stream>>>(hnb2, w1b, nullptr, gateb, nullptr, nullptr, nullptr, 2048, 8192, 2048);
    gemm_bt<1><<<dim3(64, 16), 256, 0, stream>>>(hnb2, w3b, nullptr, upb, nullptr, nullptr, nullptr, 2048, 8192, 2048);
    silu_mul<<<16384, 256, 0, stream>>>(gateb, upb, actb);
    for (int e = 0; e < 8; ++e)
        gemm_bt<3><<<dim3(16, 16), 256, 0, stream>>>(actb + (size_t)e * 2048 * 1024,
                                                     w2b + (size_t)e * 2048 * 1024,
                                                     out, nullptr, nullptr, nullptr, comb + e,
                                                     2048, 2048, 1024);
}

// Round 9
// 1364.281 us; speedup vs baseline: 3.9894x; 3.9894x over previous
//
#include <hip/hip_runtime.h>
#include <hip/hip_bf16.h>
#include <stdint.h>

typedef __bf16 bf16_t;
typedef __bf16 bf16x8v __attribute__((ext_vector_type(8)));
typedef __bf16 bf16x4v __attribute__((ext_vector_type(4)));
typedef float f32x4 __attribute__((ext_vector_type(4)));

#define DEV __device__ __forceinline__

typedef const __attribute__((address_space(1))) void gl_void_t;
typedef __attribute__((address_space(3))) void lds_void_t;

DEV void gll16(const void* g, void* l) {
    __builtin_amdgcn_global_load_lds((gl_void_t*)g, (lds_void_t*)l, 16, 0, 0);
}

DEV f32x4 mfma16(bf16x8v a, bf16x8v b, f32x4 c) {
    return __builtin_amdgcn_mfma_f32_16x16x32_bf16(a, b, c, 0, 0, 0);
}

// ---------------------------------------------------------------------------
// fp32 -> bf16 conversion (grid-stride, float4)
// ---------------------------------------------------------------------------
__global__ __launch_bounds__(256)
void f32_to_bf16_k(const float* __restrict__ in, bf16_t* __restrict__ out, size_t n4) {
    size_t stride = (size_t)gridDim.x * 256;
    for (size_t i = (size_t)blockIdx.x * 256 + threadIdx.x; i < n4; i += stride) {
        float4 v = ((const float4*)in)[i];
        bf16x4v o;
        o[0] = (bf16_t)v.x; o[1] = (bf16_t)v.y; o[2] = (bf16_t)v.z; o[3] = (bf16_t)v.w;
        ((bf16x4v*)out)[i] = o;
    }
}

// ---------------------------------------------------------------------------
// fp32 -> (hi, lo) bf16 split: hi = bf16(v), lo = bf16(v - hi).
// ---------------------------------------------------------------------------
__global__ __launch_bounds__(256)
void split_k(const float* __restrict__ in, bf16_t* __restrict__ hi,
             bf16_t* __restrict__ lo, size_t n4) {
    size_t stride = (size_t)gridDim.x * 256;
    for (size_t i = (size_t)blockIdx.x * 256 + threadIdx.x; i < n4; i += stride) {
        float4 v = ((const float4*)in)[i];
        bf16x4v h, l;
#pragma unroll
        for (int j = 0; j < 4; ++j) {
            float vv = (&v.x)[j];
            bf16_t hb = (bf16_t)vv;
            h[j] = hb;
            l[j] = (bf16_t)(vv - (float)hb);
        }
        ((bf16x4v*)hi)[i] = h;
        ((bf16x4v*)lo)[i] = l;
    }
}

// ---------------------------------------------------------------------------
// RMSNorm: fp32 [2048][2048] -> bf16 (SPLIT=0) or split hi/lo bf16 (SPLIT=1)
// ---------------------------------------------------------------------------
template<int SPLIT>
__global__ __launch_bounds__(256)
void rmsnorm_k(const float* __restrict__ x, const float* __restrict__ w,
               bf16_t* __restrict__ out, bf16_t* __restrict__ out_lo) {
    const int row = blockIdx.x, t = threadIdx.x;
    const float4* xr = (const float4*)(x + (size_t)row * 2048);
    float4 v0 = xr[t], v1 = xr[t + 256];
    float ss = v0.x*v0.x + v0.y*v0.y + v0.z*v0.z + v0.w*v0.w
             + v1.x*v1.x + v1.y*v1.y + v1.z*v1.z + v1.w*v1.w;
    for (int m = 32; m; m >>= 1) ss += __shfl_xor(ss, m);
    __shared__ float red[4];
    if ((t & 63) == 0) red[t >> 6] = ss;
    __syncthreads();
    ss = red[0] + red[1] + red[2] + red[3];
    float rinv = rsqrtf(ss * (1.0f / 2048.0f) + 1e-6f);
    const float4* wr4 = (const float4*)w;
    float4 w0 = wr4[t], w1 = wr4[t + 256];
    bf16x4v o0, o1, l0, l1;
#pragma unroll
    for (int j = 0; j < 4; ++j) {
        float y0 = (&v0.x)[j] * rinv * (&w0.x)[j];
        float y1 = (&v1.x)[j] * rinv * (&w1.x)[j];
        bf16_t h0 = (bf16_t)y0, h1 = (bf16_t)y1;
        o0[j] = h0; o1[j] = h1;
        if (SPLIT) { l0[j] = (bf16_t)(y0 - (float)h0); l1[j] = (bf16_t)(y1 - (float)h1); }
    }
    *(bf16x4v*)(out + (size_t)row * 2048 + t * 4) = o0;
    *(bf16x4v*)(out + (size_t)row * 2048 + 1024 + t * 4) = o1;
    if (SPLIT) {
        *(bf16x4v*)(out_lo + (size_t)row * 2048 + t * 4) = l0;
        *(bf16x4v*)(out_lo + (size_t)row * 2048 + 1024 + t * 4) = l1;
    }
}

// ---------------------------------------------------------------------------
// GEMM: C[M][N] = A[M][K](bf16) * B[N][K]^T(bf16).  m97-structure.
// EPI 0: Cf = acc          EPI 1: Cb = bf16(acc)
// EPI 3: Cf += comb[row*8] * acc   (comb pre-offset by expert)
// EPI 4: Cf += acc
// EPI 5: o = Cf + resid + acc; Cf = o; out2 = o   (final split-GEMM pass)
// ---------------------------------------------------------------------------
template<int EPI>
__global__ __launch_bounds__(256)
void gemm_bt(const bf16_t* __restrict__ A, const bf16_t* __restrict__ B,
             float* __restrict__ Cf, bf16_t* __restrict__ Cb,
             const float* __restrict__ resid, float* __restrict__ out2,
             const float* __restrict__ comb,
             int M, int N, int K) {
    __shared__ bf16_t As[128 * 64];
    __shared__ bf16_t Bs[128 * 64];
    const int t = threadIdx.x;
    const int w = t >> 6, l = t & 63;
    const int lr = l & 15, lg = l >> 4;
    const int wr = w >> 1, wc = w & 1;
    const int bm = blockIdx.y, bn = blockIdx.x;
    const bf16_t* Ab = A + (size_t)bm * 128 * K;
    const bf16_t* Bb = B + (size_t)bn * 128 * K;
    const int srow = t >> 3;
    const int scol = (t & 7) * 8;
    f32x4 acc[4][4] = {};
    for (int kt = 0; kt < K; kt += 64) {
        __syncthreads();
#pragma unroll
        for (int c = 0; c < 4; ++c) {
            gll16(Ab + (size_t)(c * 32 + srow) * K + kt + scol, As + (c * 32 + srow) * 64 + scol);
            gll16(Bb + (size_t)(c * 32 + srow) * K + kt + scol, Bs + (c * 32 + srow) * 64 + scol);
        }
        __syncthreads();
#pragma unroll
        for (int kk = 0; kk < 2; ++kk) {
            bf16x8v af[4], bfr[4];
#pragma unroll
            for (int m = 0; m < 4; ++m)
                af[m] = *(const bf16x8v*)(As + (wr * 64 + m * 16 + lr) * 64 + kk * 32 + lg * 8);
#pragma unroll
            for (int n = 0; n < 4; ++n)
                bfr[n] = *(const bf16x8v*)(Bs + (wc * 64 + n * 16 + lr) * 64 + kk * 32 + lg * 8);
#pragma unroll
            for (int m = 0; m < 4; ++m)
#pragma unroll
                for (int n = 0; n < 4; ++n)
                    acc[m][n] = mfma16(af[m], bfr[n], acc[m][n]);
        }
    }
#pragma unroll
    for (int m = 0; m < 4; ++m) {
#pragma unroll
        for (int r = 0; r < 4; ++r) {
            int gr = bm * 128 + wr * 64 + m * 16 + lg * 4 + r;
            float cw = 0.f;
            if (EPI == 3) cw = comb[(size_t)gr * 8];
#pragma unroll
            for (int n = 0; n < 4; ++n) {
                int gc = bn * 128 + wc * 64 + n * 16 + lr;
                size_t off = (size_t)gr * N + gc;
                float v = acc[m][n][r];
                if (EPI == 0) {
                    Cf[off] = v;
                } else if (EPI == 1) {
                    Cb[off] = (bf16_t)v;
                } else if (EPI == 3) {
                    Cf[off] += cw * v;
                } else if (EPI == 4) {
                    Cf[off] += v;
                } else {
                    float o = Cf[off] + resid[off] + v;
                    Cf[off] = o;
                    out2[off] = o;
                }
            }
        }
    }
}

// ---------------------------------------------------------------------------
// q/k RMSNorm + partial RoPE (RD=64); q,k emitted as SPLIT bf16 hi/lo
// (q pre-scaled by 1/sqrt(128)); v emitted fp32 [4][2048][128].
// ---------------------------------------------------------------------------
__global__ __launch_bounds__(256)
void qknorm_rope_split(const float* __restrict__ qkv, const float* __restrict__ qn_w,
                       const float* __restrict__ kn_w, const float* __restrict__ cosb,
                       const float* __restrict__ sinb,
                       bf16_t* __restrict__ qhi, bf16_t* __restrict__ qlo,
                       bf16_t* __restrict__ khi, bf16_t* __restrict__ klo,
                       float* __restrict__ vrf) {
    const int s = blockIdx.x, t = threadIdx.x;
    const float* row = qkv + (size_t)s * 3072;
    float ssq = 0.f;
#pragma unroll
    for (int rep = 0; rep < 8; ++rep) { float v = row[t + rep * 256]; ssq += v * v; }
    float a = row[2048 + t], b = row[2048 + t + 256];
    float ssk = a * a + b * b;
    for (int m = 32; m; m >>= 1) { ssq += __shfl_xor(ssq, m); ssk += __shfl_xor(ssk, m); }
    __shared__ float redq[4], redk[4];
    if ((t & 63) == 0) { redq[t >> 6] = ssq; redk[t >> 6] = ssk; }
    __syncthreads();
    ssq = redq[0] + redq[1] + redq[2] + redq[3];
    ssk = redk[0] + redk[1] + redk[2] + redk[3];
    float rq = rsqrtf(ssq * (1.f / 2048.f) + 1e-6f);
    float rk = rsqrtf(ssk * (1.f / 512.f) + 1e-6f);
#pragma unroll
    for (int rep = 0; rep < 8; ++rep) {
        int i = t + rep * 256;
        int hd = i & 127, hh = i >> 7;
        float v = row[i] * rq * qn_w[i];
        float o;
        if (hd < 64) {
            float vp = row[i ^ 32] * rq * qn_w[i ^ 32];
            float cs = cosb[s * 64 + hd], sn = sinb[s * 64 + hd];
            o = v * cs + ((hd < 32) ? -vp : vp) * sn;
        } else o = v;
        o *= 0.08838834764831845f;
        bf16_t hb = (bf16_t)o;
        size_t idx = ((size_t)hh * 2048 + s) * 128 + hd;
        qhi[idx] = hb;
        qlo[idx] = (bf16_t)(o - (float)hb);
    }
#pragma unroll
    for (int rep = 0; rep < 2; ++rep) {
        int i2 = t + rep * 256;
        int hd = i2 & 127, hh = i2 >> 7;
        float v = row[2048 + i2] * rk * kn_w[i2];
        float o;
        if (hd < 64) {
            float vp = row[2048 + (i2 ^ 32)] * rk * kn_w[i2 ^ 32];
            float cs = cosb[s * 64 + hd], sn = sinb[s * 64 + hd];
            o = v * cs + ((hd < 32) ? -vp : vp) * sn;
        } else o = v;
        bf16_t hb = (bf16_t)o;
        size_t idx = ((size_t)hh * 2048 + s) * 128 + hd;
        khi[idx] = hb;
        klo[idx] = (bf16_t)(o - (float)hb);
    }
#pragma unroll
    for (int rep = 0; rep < 2; ++rep) {
        int i2 = t + rep * 256;
        int hd = i2 & 127, hh = i2 >> 7;
        vrf[((size_t)hh * 2048 + s) * 128 + hd] = row[2560 + i2];
    }
}

// ---------------------------------------------------------------------------
// V transpose+split: vrf[hk][s][d] fp32 -> vthi/vtlo[hk][d][s] bf16
// ---------------------------------------------------------------------------
__global__ __launch_bounds__(256)
void vtrans_split(const float* __restrict__ vrf, bf16_t* __restrict__ vthi,
                  bf16_t* __restrict__ vtlo) {
    __shared__ float tile[32][33];
    int hk = blockIdx.z, s0 = blockIdx.x * 32, d0 = blockIdx.y * 32;
    int tx = threadIdx.x & 31, ty = threadIdx.x >> 5;
    for (int i = ty; i < 32; i += 8)
        tile[i][tx] = vrf[((size_t)hk * 2048 + s0 + i) * 128 + d0 + tx];
    __syncthreads();
    for (int i = ty; i < 32; i += 8) {
        float v = tile[tx][i];
        bf16_t hb = (bf16_t)v;
        size_t idx = ((size_t)hk * 128 + d0 + i) * 2048 + s0 + tx;
        vthi[idx] = hb;
        vtlo[idx] = (bf16_t)(v - (float)hb);
    }
}

// ---------------------------------------------------------------------------
// Split-bf16 flash attention, causal GQA. 4 waves, 64 q-rows/block, KV tile 32.
// QK^T = qh*kh + qh*kl + ql*kh;  PV = ph*vh + ph*vl + pl*vh  (fp32 softmax).
// LDS bank-conflict-free via XOR slot swizzle:
//   K  (row stride 128 el, 16 slots): slot ^= row&7  [G4/T2, rule 21]
//   V^T/P (row stride 32 el, 4 slots): slot ^= row&3
// global_load_lds: linear LDS dest + inverse-swizzled per-lane GLOBAL source.
// ---------------------------------------------------------------------------
__global__ __launch_bounds__(256)
void flash_attn_split(const bf16_t* __restrict__ qhi, const bf16_t* __restrict__ qlo,
                      const bf16_t* __restrict__ khi, const bf16_t* __restrict__ klo,
                      const bf16_t* __restrict__ vthi, const bf16_t* __restrict__ vtlo,
                      float* __restrict__ attnf) {
    __shared__ bf16_t Khs[32 * 128], Kls[32 * 128];
    __shared__ bf16_t Vhs[128 * 32], Vls[128 * 32];
    __shared__ bf16_t Phs[4 * 16 * 32], Pls[4 * 16 * 32];
    const int t = threadIdx.x, w = t >> 6, l = t & 63, lr = l & 15, lg = l >> 4;
    const int qb = blockIdx.x, h = blockIdx.y, hk = h >> 2;
    const int q0w = qb * 64 + w * 16;
    const bf16_t* Kbh = khi + (size_t)hk * 2048 * 128;
    const bf16_t* Kbl = klo + (size_t)hk * 2048 * 128;
    const bf16_t* Vbh = vthi + (size_t)hk * 128 * 2048;
    const bf16_t* Vbl = vtlo + (size_t)hk * 128 * 2048;
    bf16x8v qfh[4], qfl[4];
    {
        const bf16_t* Qh = qhi + ((size_t)h * 2048 + q0w + lr) * 128 + lg * 8;
        const bf16_t* Ql = qlo + ((size_t)h * 2048 + q0w + lr) * 128 + lg * 8;
#pragma unroll
        for (int c = 0; c < 4; ++c) {
            qfh[c] = *(const bf16x8v*)(Qh + c * 32);
            qfl[c] = *(const bf16x8v*)(Ql + c * 32);
        }
    }
    f32x4 acc[8] = {};
    float m_run[4], l_run[4];
#pragma unroll
    for (int r = 0; r < 4; ++r) { m_run[r] = -__builtin_inff(); l_run[r] = 0.f; }
    const int nt = 2 * qb + 2;
    // staging lane geometry
    const int krow = t >> 4;                 // 16 rows per 4KB inst
    const int kslot = (t & 15) ^ (krow & 7); // inverse-swizzled global slot
    const int kdst = (t & 15) * 8;           // linear LDS elem offset
    const int vrow = t >> 2;                 // 64 rows per inst
    const int vslot = (t & 3) ^ (vrow & 3);
    const int vdst = (t & 3) * 8;
    for (int ti = 0; ti < nt; ++ti) {
        const int kv0 = ti * 32;
        __syncthreads();
#pragma unroll
        for (int c = 0; c < 2; ++c) {
            gll16(Kbh + (size_t)(kv0 + c * 16 + krow) * 128 + kslot * 8,
                  Khs + (c * 16 + krow) * 128 + kdst);
            gll16(Kbl + (size_t)(kv0 + c * 16 + krow) * 128 + kslot * 8,
                  Kls + (c * 16 + krow) * 128 + kdst);
            gll16(Vbh + (size_t)(c * 64 + vrow) * 2048 + kv0 + vslot * 8,
                  Vhs + (c * 64 + vrow) * 32 + vdst);
            gll16(Vbl + (size_t)(c * 64 + vrow) * 2048 + kv0 + vslot * 8,
                  Vls + (c * 64 + vrow) * 32 + vdst);
        }
        __syncthreads();
        if (kv0 <= q0w + 15) {
            f32x4 sa[2] = {};
#pragma unroll
            for (int kvc = 0; kvc < 2; ++kvc) {
                const int rk = kvc * 16 + lr;
#pragma unroll
                for (int c = 0; c < 4; ++c) {
                    const int koff = rk * 128 + (((c * 4 + lg) ^ (lr & 7)) * 8);
                    bf16x8v kfh = *(const bf16x8v*)(Khs + koff);
                    bf16x8v kfl = *(const bf16x8v*)(Kls + koff);
                    sa[kvc] = mfma16(qfh[c], kfh, sa[kvc]);
                    sa[kvc] = mfma16(qfh[c], kfl, sa[kvc]);
                    sa[kvc] = mfma16(qfl[c], kfh, sa[kvc]);
                }
            }
#pragma unroll
            for (int r = 0; r < 4; ++r) {
                int q = q0w + lg * 4 + r;
#pragma unroll
                for (int kvc = 0; kvc < 2; ++kvc) {
                    int kv = kv0 + kvc * 16 + lr;
                    if (kv > q) sa[kvc][r] = -__builtin_inff();
                }
            }
#pragma unroll
            for (int r = 0; r < 4; ++r) {
                float mx = fmaxf(sa[0][r], sa[1][r]);
                mx = fmaxf(mx, __shfl_xor(mx, 1));
                mx = fmaxf(mx, __shfl_xor(mx, 2));
                mx = fmaxf(mx, __shfl_xor(mx, 4));
                mx = fmaxf(mx, __shfl_xor(mx, 8));
                float mnew = fmaxf(m_run[r], mx);
                float scl = __expf(m_run[r] - mnew);
                float p0 = __expf(sa[0][r] - mnew);
                float p1 = __expf(sa[1][r] - mnew);
                float rs = p0 + p1;
                rs += __shfl_xor(rs, 1); rs += __shfl_xor(rs, 2);
                rs += __shfl_xor(rs, 4); rs += __shfl_xor(rs, 8);
                m_run[r] = mnew;
                l_run[r] = l_run[r] * scl + rs;
                // P write, swizzled: row = lg*4+r (row&3 == r), kv cols lr and 16+lr
                const int prow = w * 16 + lg * 4 + r;
                bf16_t ph0 = (bf16_t)p0, ph1 = (bf16_t)p1;
                int o0 = prow * 32 + (((lr >> 3) ^ r) * 8) + (lr & 7);
                int o1 = prow * 32 + ((((16 + lr) >> 3) ^ r) * 8) + (lr & 7);
                Phs[o0] = ph0; Pls[o0] = (bf16_t)(p0 - (float)ph0);
                Phs[o1] = ph1; Pls[o1] = (bf16_t)(p1 - (float)ph1);
#pragma unroll
                for (int dc = 0; dc < 8; ++dc) acc[dc][r] *= scl;
            }
            const int poff = (w * 16 + lr) * 32 + ((lg ^ (lr & 3)) * 8);
            bf16x8v pah = *(const bf16x8v*)(Phs + poff);
            bf16x8v pal = *(const bf16x8v*)(Pls + poff);
#pragma unroll
            for (int dc = 0; dc < 8; ++dc) {
                const int voff = (dc * 16 + lr) * 32 + ((lg ^ (lr & 3)) * 8);
                bf16x8v vfh = *(const bf16x8v*)(Vhs + voff);
                bf16x8v vfl = *(const bf16x8v*)(Vls + voff);
                acc[dc] = mfma16(pah, vfh, acc[dc]);
                acc[dc] = mfma16(pah, vfl, acc[dc]);
                acc[dc] = mfma16(pal, vfh, acc[dc]);
            }
        }
    }
#pragma unroll
    for (int r = 0; r < 4; ++r) {
        float inv = 1.0f / l_run[r];
        int q = q0w + lg * 4 + r;
#pragma unroll
        for (int dc = 0; dc < 8; ++dc)
            attnf[(size_t)q * 2048 + h * 128 + dc * 16 + lr] = acc[dc][r] * inv;
    }
}

// ---------------------------------------------------------------------------
// Router (fp64): rmsnorm(h)*ln2_w @ gate_w^T -> sigmoid -> top2 -> comb[T][8]
// ---------------------------------------------------------------------------
__global__ __launch_bounds__(256)
void routing_k(const float* __restrict__ h, const float* __restrict__ ln2w,
               const float* __restrict__ gate_w, const float* __restrict__ bias_corr,
               float* __restrict__ comb) {
    const int s = blockIdx.x, t = threadIdx.x;
    const float* xr = h + (size_t)s * 2048;
    float xv[8];
    double ss = 0.0;
#pragma unroll
    for (int rep = 0; rep < 8; ++rep) {
        xv[rep] = xr[t + rep * 256];
        ss += (double)xv[rep] * (double)xv[rep];
    }
    for (int m = 32; m; m >>= 1) ss += __shfl_xor(ss, m);
    __shared__ double redd[4];
    if ((t & 63) == 0) redd[t >> 6] = ss;
    __syncthreads();
    ss = redd[0] + redd[1] + redd[2] + redd[3];
    double rinv = 1.0 / sqrt(ss * (1.0 / 2048.0) + 1e-6);
    double part[8];
#pragma unroll
    for (int e = 0; e < 8; ++e) part[e] = 0.0;
#pragma unroll
    for (int rep = 0; rep < 8; ++rep) {
        int i = t + rep * 256;
        double x = (double)xv[rep] * rinv * (double)ln2w[i];
#pragma unroll
        for (int e = 0; e < 8; ++e)
            part[e] += x * (double)gate_w[e * 2048 + i];
    }
#pragma unroll
    for (int e = 0; e < 8; ++e)
        for (int m = 32; m; m >>= 1) part[e] += __shfl_xor(part[e], m);
    __shared__ double red8[4][8];
    if ((t & 63) == 0) {
#pragma unroll
        for (int e = 0; e < 8; ++e) red8[t >> 6][e] = part[e];
    }
    __syncthreads();
    if (t == 0) {
        double rw[8], sc[8];
#pragma unroll
        for (int e = 0; e < 8; ++e) {
            double v = red8[0][e] + red8[1][e] + red8[2][e] + red8[3][e];
            rw[e] = 1.0 / (1.0 + exp(-v));
            sc[e] = rw[e] + (double)bias_corr[e];
        }
        int i0 = 0;
#pragma unroll
        for (int e = 1; e < 8; ++e) if (sc[e] > sc[i0]) i0 = e;
        int i1 = (i0 == 0) ? 1 : 0;
#pragma unroll
        for (int e = 0; e < 8; ++e) { if (e != i0 && sc[e] > sc[i1]) i1 = e; }
        double denom = rw[i0] + rw[i1];
#pragma unroll
        for (int e = 0; e < 8; ++e) {
            float wv = 0.f;
            if (e == i0) wv = (float)(rw[i0] / denom);
            else if (e == i1) wv = (float)(rw[i1] / denom);
            comb[s * 8 + e] = wv;
        }
    }
}

// ---------------------------------------------------------------------------
// act[e][t][f] = silu(gate[t][e*1024+f]) * up[t][e*1024+f]   (bf16)
// ---------------------------------------------------------------------------
__global__ __launch_bounds__(256)
void silu_mul(const bf16_t* __restrict__ g, const bf16_t* __restrict__ u,
              bf16_t* __restrict__ act) {
    size_t idx = ((size_t)blockIdx.x * 256 + threadIdx.x) * 4;
    int e = (int)(idx >> 21);
    int rem = (int)(idx & ((1u << 21) - 1));
    int tt = rem >> 10, f = rem & 1023;
    size_t gi = (size_t)tt * 8192 + e * 1024 + f;
    bf16x4v gv = *(const bf16x4v*)(g + gi);
    bf16x4v uv = *(const bf16x4v*)(u + gi);
    bf16x4v o;
#pragma unroll
    for (int j = 0; j < 4; ++j) {
        float gf = (float)gv[j], uf = (float)uv[j];
        float sl = gf / (1.f + __expf(-gf));
        o[j] = (bf16_t)(sl * uf);
    }
    *(bf16x4v*)(act + idx) = o;
}

// ---------------------------------------------------------------------------
extern "C" void kernel_launch(void* const* d_in, const int* in_sizes, int n_in,
                              void* d_out, int out_size, void* d_ws, size_t ws_size,
                              hipStream_t stream) {
    const float* hidden = (const float*)d_in[0];
    const float* cosb   = (const float*)d_in[1];
    const float* sinb   = (const float*)d_in[2];
    const float* ln1w   = (const float*)d_in[3];
    const float* ln2w   = (const float*)d_in[4];
    const float* q_w    = (const float*)d_in[5];
    const float* k_w    = (const float*)d_in[6];
    const float* v_w    = (const float*)d_in[7];
    const float* o_w    = (const float*)d_in[8];
    const float* qn_w   = (const float*)d_in[9];
    const float* kn_w   = (const float*)d_in[10];
    const float* gate_w = (const float*)d_in[11];
    const float* w1     = (const float*)d_in[12];
    const float* w2     = (const float*)d_in[13];
    const float* w3     = (const float*)d_in[14];
    const float* bias_c = (const float*)d_in[15];
    float* out = (float*)d_out;
    (void)in_sizes; (void)n_in; (void)out_size; (void)ws_size;

    const size_t MB = 1048576;
    char* ws = (char*)d_ws;
    // fixed region
    float*  hres = (float*)ws;                         // 16.78 MB
    bf16_t* hnb2 = (bf16_t*)(ws + 17 * MB);            // 8.4 MB
    float*  comb = (float*)(ws + 26 * MB);             // 64 KB
    char*   UW   = ws + 27 * MB;                       // 96 MiB weight union
    char*   UA   = ws + 123 * MB;                      // 96 MiB activation union
    // UW phase 1 (attention weights, split)
    bf16_t* whiq = (bf16_t*)(UW);                      // 12.6 MB
    bf16_t* wloq = (bf16_t*)(UW + 13 * MB);
    bf16_t* wohi = (bf16_t*)(UW + 26 * MB);            // 8.4 MB
    bf16_t* wolo = (bf16_t*)(UW + 35 * MB);
    bf16_t* hnhi = (bf16_t*)(UW + 44 * MB);            // 8.4 MB
    bf16_t* hnlo = (bf16_t*)(UW + 53 * MB);
    // UW phase 2 (MoE weights, bf16) -- written after O-proj completes
    bf16_t* w1b  = (bf16_t*)(UW);                      // 32 MB
    bf16_t* w3b  = (bf16_t*)(UW + 32 * MB);
    bf16_t* w2b  = (bf16_t*)(UW + 64 * MB);
    // UA phase 1
    float*  qkvf  = (float*)(UA);                      // 25.2 MB
    bf16_t* qhi   = (bf16_t*)(UA + 26 * MB);           // 8.4 MB
    bf16_t* qlo   = (bf16_t*)(UA + 35 * MB);           // 8.4 MB
    bf16_t* khi   = (bf16_t*)(UA + 44 * MB);           // 2.1 MB
    bf16_t* klo   = (bf16_t*)(UA + 47 * MB);           // 2.1 MB
    float*  vrf   = (float*)(UA + 50 * MB);            // 4.2 MB
    bf16_t* vthi  = (bf16_t*)(UA + 55 * MB);           // 2.1 MB
    bf16_t* vtlo  = (bf16_t*)(UA + 58 * MB);           // 2.1 MB
    float*  attnf = (float*)(UA + 61 * MB);            // 16.8 MB
    bf16_t* aohi  = (bf16_t*)(UA + 78 * MB);           // 8.4 MB
    bf16_t* aolo  = (bf16_t*)(UA + 87 * MB);           // 8.4 MB
    // UA phase 2
    bf16_t* gateb = (bf16_t*)(UA);                     // 32 MB
    bf16_t* upb   = (bf16_t*)(UA + 32 * MB);
    bf16_t* actb  = (bf16_t*)(UA + 64 * MB);

    // ---- attention-path weight splits (hi/lo) ----
    split_k<<<1024, 256, 0, stream>>>(q_w, whiq, wloq, 2048ull * 2048 / 4);
    split_k<<<512, 256, 0, stream>>>(k_w, whiq + 2048ull * 2048, wloq + 2048ull * 2048, 512ull * 2048 / 4);
    split_k<<<512, 256, 0, stream>>>(v_w, whiq + 2560ull * 2048, wloq + 2560ull * 2048, 512ull * 2048 / 4);
    split_k<<<1024, 256, 0, stream>>>(o_w, wohi, wolo, 2048ull * 2048 / 4);

    // ---- ln1 (split) + QKV projection in split-bf16 (4 passes, fp32 out) ----
    rmsnorm_k<1><<<2048, 256, 0, stream>>>(hidden, ln1w, hnhi, hnlo);
    gemm_bt<0><<<dim3(24, 16), 256, 0, stream>>>(hnhi, whiq, qkvf, nullptr, nullptr, nullptr, nullptr, 2048, 3072, 2048);
    gemm_bt<4><<<dim3(24, 16), 256, 0, stream>>>(hnhi, wloq, qkvf, nullptr, nullptr, nullptr, nullptr, 2048, 3072, 2048);
    gemm_bt<4><<<dim3(24, 16), 256, 0, stream>>>(hnlo, whiq, qkvf, nullptr, nullptr, nullptr, nullptr, 2048, 3072, 2048);
    gemm_bt<4><<<dim3(24, 16), 256, 0, stream>>>(hnlo, wloq, qkvf, nullptr, nullptr, nullptr, nullptr, 2048, 3072, 2048);

    // ---- q/k norm + RoPE (split out) + V transpose/split + MFMA attention ----
    qknorm_rope_split<<<2048, 256, 0, stream>>>(qkvf, qn_w, kn_w, cosb, sinb, qhi, qlo, khi, klo, vrf);
    vtrans_split<<<dim3(64, 4, 4), 256, 0, stream>>>(vrf, vthi, vtlo);
    flash_attn_split<<<dim3(32, 16), 256, 0, stream>>>(qhi, qlo, khi, klo, vthi, vtlo, attnf);

    // ---- O-proj in split-bf16 (4 passes), final pass adds residual, writes out ----
    split_k<<<1024, 256, 0, stream>>>(attnf, aohi, aolo, 2048ull * 2048 / 4);
    gemm_bt<0><<<dim3(16, 16), 256, 0, stream>>>(aohi, wohi, hres, nullptr, nullptr, nullptr, nullptr, 2048, 2048, 2048);
    gemm_bt<4><<<dim3(16, 16), 256, 0, stream>>>(aohi, wolo, hres, nullptr, nullptr, nullptr, nullptr, 2048, 2048, 2048);
    gemm_bt<4><<<dim3(16, 16), 256, 0, stream>>>(aolo, wohi, hres, nullptr, nullptr, nullptr, nullptr, 2048, 2048, 2048);
    gemm_bt<5><<<dim3(16, 16), 256, 0, stream>>>(aolo, wolo, hres, nullptr, hidden, out, nullptr, 2048, 2048, 2048);

    // ---- MoE block (routing fp64 on accurate hres; compute bf16) ----
    rmsnorm_k<0><<<2048, 256, 0, stream>>>(hres, ln2w, hnb2, nullptr);
    routing_k<<<2048, 256, 0, stream>>>(hres, ln2w, gate_w, bias_c, comb);
    f32_to_bf16_k<<<2048, 256, 0, stream>>>(w1, w1b, 8ull * 1024 * 2048 / 4);
    f32_to_bf16_k<<<2048, 256, 0, stream>>>(w3, w3b, 8ull * 1024 * 2048 / 4);
    f32_to_bf16_k<<<2048, 256, 0, stream>>>(w2, w2b, 8ull * 2048 * 1024 / 4);
    gemm_bt<1><<<dim3(64, 16), 256, 0, stream>>>(hnb2, w1b, nullptr, gateb, nullptr, nullptr, nullptr, 2048, 8192, 2048);
    gemm_bt<1><<<dim3(64, 16), 256, 0, stream>>>(hnb2, w3b, nullptr, upb, nullptr, nullptr, nullptr, 2048, 8192, 2048);
    silu_mul<<<16384, 256, 0, stream>>>(gateb, upb, actb);
    for (int e = 0; e < 8; ++e)
        gemm_bt<3><<<dim3(16, 16), 256, 0, stream>>>(actb + (size_t)e * 2048 * 1024,
                                                     w2b + (size_t)e * 2048 * 1024,
                                                     out, nullptr, nullptr, nullptr, comb + e,
                                                     2048, 2048, 1024);
}